// Round 1
// baseline (1021.174 us; speedup 1.0000x reference)
//
#include <hip/hip_runtime.h>
#include <hip/hip_bf16.h>

#define H 128

using bf16x8  = __attribute__((ext_vector_type(8))) short;  // 8 bf16 = 4 VGPRs
using floatx4 = __attribute__((ext_vector_type(4))) float;

static __device__ __forceinline__ short f2bf(float f) {
  union { float f; unsigned u; } v; v.f = f;
  unsigned r = v.u + 0x7fffu + ((v.u >> 16) & 1u);  // RNE
  return (short)(r >> 16);
}
static __device__ __forceinline__ float bf2f(short s) {
  union { unsigned u; float f; } v; v.u = ((unsigned)(unsigned short)s) << 16;
  return v.f;
}

// ---- degree counts (int) ----
__global__ void count_edges(const int* __restrict__ src, const int* __restrict__ dst,
                            int E, int* __restrict__ cnt_s, int* __restrict__ cnt_d) {
  int e = blockIdx.x * blockDim.x + threadIdx.x;
  if (e >= E) return;
  atomicAdd(&cnt_s[src[e]], 1);
  atomicAdd(&cnt_d[dst[e]], 1);
}

__global__ void rcp_from_cnt(const int* __restrict__ cnt, float* __restrict__ r, int n) {
  int i = blockIdx.x * blockDim.x + threadIdx.x;
  if (i < n) r[i] = 1.0f / fmaxf((float)cnt[i], 1.0f);
}

// ---- 3-kernel exclusive scan over 4 contiguous count arrays ----
__global__ __launch_bounds__(256) void scan_k1(const int* __restrict__ cnt, int* __restrict__ off,
                                               int* __restrict__ bsums, int4 starts, int4 lens) {
  int a = blockIdx.y;
  int start = ((const int*)&starts)[a];
  int len   = ((const int*)&lens)[a];
  int chunk = blockIdx.x * 1024;
  if (chunk >= len) return;
  const int* in = cnt + start;
  int* out = off + start;
  int tid = threadIdx.x;
  int base = chunk + tid * 4;
  int v[4];
#pragma unroll
  for (int j = 0; j < 4; ++j) v[j] = (base + j < len) ? in[base + j] : 0;
  int s = v[0] + v[1] + v[2] + v[3];
  __shared__ int lds[256];
  lds[tid] = s; __syncthreads();
  for (int o = 1; o < 256; o <<= 1) {
    int t = (tid >= o) ? lds[tid - o] : 0;
    __syncthreads();
    lds[tid] += t;
    __syncthreads();
  }
  int run = lds[tid] - s;  // exclusive prefix of this thread's 4
#pragma unroll
  for (int j = 0; j < 4; ++j) { if (base + j < len) out[base + j] = run; run += v[j]; }
  if (tid == 255) bsums[a * 256 + blockIdx.x] = lds[255];
}

__global__ __launch_bounds__(256) void scan_k2(int* __restrict__ bsums, int4 lens) {
  int a = blockIdx.x;
  int len = ((const int*)&lens)[a];
  int nb = (len + 1023) >> 10;
  int tid = threadIdx.x;
  int s = (tid < nb) ? bsums[a * 256 + tid] : 0;  // guard: slots >= nb are poisoned
  __shared__ int lds[256];
  lds[tid] = s; __syncthreads();
  for (int o = 1; o < 256; o <<= 1) {
    int t = (tid >= o) ? lds[tid - o] : 0;
    __syncthreads();
    lds[tid] += t;
    __syncthreads();
  }
  bsums[a * 256 + tid] = lds[tid] - s;
}

__global__ __launch_bounds__(256) void scan_k3(int* __restrict__ off, const int* __restrict__ bsums,
                                               int4 starts, int4 lens) {
  int a = blockIdx.y;
  int start = ((const int*)&starts)[a];
  int len   = ((const int*)&lens)[a];
  int chunk = blockIdx.x * 1024;
  if (chunk >= len) return;
  int add = bsums[a * 256 + blockIdx.x];
  int* out = off + start;
  int base = chunk + threadIdx.x * 4;
#pragma unroll
  for (int j = 0; j < 4; ++j) if (base + j < len) out[base + j] += add;
}

// ---- CSR fill (both directions of one relation) ----
__global__ void fill_csr(const int* __restrict__ src, const int* __restrict__ dst, int E,
                         const int* __restrict__ off_d, int* __restrict__ cur_d, int* __restrict__ sort_d,
                         const int* __restrict__ off_s, int* __restrict__ cur_s, int* __restrict__ sort_s) {
  int e = blockIdx.x * blockDim.x + threadIdx.x;
  if (e >= E) return;
  int s = src[e], d = dst[e];
  sort_d[off_d[d] + atomicAdd(&cur_d[d], 1)] = s;  // neighbors of dst node (src ids)
  sort_s[off_s[s] + atomicAdd(&cur_s[s], 1)] = d;  // neighbors of src node (dst ids)
}

// ---- fp32 -> bf16 streaming convert ----
__global__ void cvt_bf16(const float* __restrict__ in, short* __restrict__ out, int n) {
  int idx = (blockIdx.x * blockDim.x + threadIdx.x) * 4;
  if (idx >= n) return;
  float4 v = *(const float4*)(in + idx);
  short4 o = { f2bf(v.x), f2bf(v.y), f2bf(v.z), f2bf(v.w) };
  *(short4*)(out + idx) = o;
}

// ---- weight prep: bf16 convert, combine Wr pair and bias pair per (layer,type).
// Weights are written in MFMA B-fragment order so fused_gemm loads them as
// perfectly coalesced 1KB chunks straight from global (L1/L2-hot, no LDS):
//   fragment (jt,kk), lane l holds 8 bf16 of W[(jt*16 + (l&15))][kk*32 + (l>>4)*8 + j]
//   stored at ((jt*4+kk)*64 + l)*8 + j
static __device__ __forceinline__ int wswz(int e) {
  int n = e >> 7, k = e & 127;          // W row-major [n][k]
  int jt = n >> 4, r = n & 15;
  int kk = k >> 5, q = (k >> 3) & 3, j = k & 7;
  return (((jt * 4 + kk) * 64 + q * 16 + r) << 3) + j;
}
__global__ void prep_weights(const float* __restrict__ W_l, const float* __restrict__ b_l,
                             const float* __restrict__ W_r,
                             short* __restrict__ Wbf, float* __restrict__ bc) {
  int i = blockIdx.x * blockDim.x + threadIdx.x;
  if (i >= 4 * 16384) return;
  int s = i >> 14, e = i & 16383;
  int l = s >> 1, t = s & 1;
  int rA = t ? 1 : 0, rB = t ? 3 : 2;
  const float* WA = W_l + ((size_t)(l * 4 + rA) << 14);
  const float* WB = W_l + ((size_t)(l * 4 + rB) << 14);
  const float* RA = W_r + ((size_t)(l * 4 + rA) << 14);
  const float* RB = W_r + ((size_t)(l * 4 + rB) << 14);
  short* o = Wbf + (size_t)s * 3 * 16384;
  int d = wswz(e);
  o[d]             = f2bf(WA[e]);
  o[16384 + d]     = f2bf(WB[e]);
  o[2 * 16384 + d] = f2bf(RA[e] + RB[e]);
  if (e < H) bc[s * H + e] = b_l[(l * 4 + rA) * H + e] + b_l[(l * 4 + rB) * H + e];
}

// ---- gather-based segment mean: 16 lanes per node, bf16x8 per lane, fp32 accum ----
__global__ __launch_bounds__(256) void aggregate(
    const bf16x8* __restrict__ xbf,
    const int* __restrict__ sV, const int* __restrict__ offV, const int* __restrict__ cntV,
    const float* __restrict__ rV,
    const int* __restrict__ sL, const int* __restrict__ offL, const int* __restrict__ cntL,
    const float* __restrict__ rL,
    bf16x8* __restrict__ mV, bf16x8* __restrict__ mL, int N) {
  int t = blockIdx.x * 256 + threadIdx.x;
  int node = t >> 4, c = t & 15;
  if (node >= N) return;
  float acc[8];
  {
    int o = offV[node], n = cntV[node];
#pragma unroll
    for (int j = 0; j < 8; ++j) acc[j] = 0.f;
    for (int i = o; i < o + n; ++i) {
      bf16x8 v = xbf[(size_t)sV[i] * 16 + c];
#pragma unroll
      for (int j = 0; j < 8; ++j) acc[j] += bf2f(v[j]);
    }
    float r = rV[node];
    bf16x8 w;
#pragma unroll
    for (int j = 0; j < 8; ++j) w[j] = f2bf(acc[j] * r);
    mV[(size_t)node * 16 + c] = w;
  }
  {
    int o = offL[node], n = cntL[node];
#pragma unroll
    for (int j = 0; j < 8; ++j) acc[j] = 0.f;
    for (int i = o; i < o + n; ++i) {
      bf16x8 v = xbf[(size_t)sL[i] * 16 + c];
#pragma unroll
      for (int j = 0; j < 8; ++j) acc[j] += bf2f(v[j]);
    }
    float r = rL[node];
    bf16x8 w;
#pragma unroll
    for (int j = 0; j < 8; ++j) w[j] = f2bf(acc[j] * r);
    mL[(size_t)node * 16 + c] = w;
  }
}

// ---- fused SAGE transform: out = mV@WA.T + mL@WB.T + x@WRc.T + b [, ReLU]
// v2: barrier-free, LDS-free. Each wave owns a 32-row x 128-col tile
// (2 MFMA row-tiles, acc = 64 VGPRs). Weights were pre-swizzled to fragment
// order by prep_weights, so every B-fragment is one coalesced 1KB
// global_load_dwordx4 (96KB set, L1/L2-resident chip-wide). A-loads for all
// 4 k-slices are hoisted per matrix (8 independent loads in flight). No
// __syncthreads -> waves free-run and hide each other's memory latency.
// A frag: A[m=lane&15][k=quad*8+j]; B frag: B[k][n=lane&15]=W[n][k];
// C/D: col=lane&15, row=quad*4+reg.
__global__ __launch_bounds__(256) void fused_gemm(
    const short* __restrict__ mV, const short* __restrict__ mL, const short* __restrict__ xb,
    const short* __restrict__ Wset, const float* __restrict__ bias,
    float* __restrict__ out32, short* __restrict__ out16, int N, int relu) {
  int tid = threadIdx.x;
  int wave = tid >> 6, lane = tid & 63;
  int r = lane & 15, quad = lane >> 4;
  int row_base = blockIdx.x * 128 + wave * 32;  // 2 row-tiles of 16 per wave
  if (row_base >= N) return;

  floatx4 acc[2][8];
#pragma unroll
  for (int t = 0; t < 2; ++t)
#pragma unroll
    for (int j = 0; j < 8; ++j) acc[t][j] = floatx4{0.f, 0.f, 0.f, 0.f};

#pragma unroll
  for (int m = 0; m < 3; ++m) {
    const short* X = (m == 0) ? mV : (m == 1) ? mL : xb;  // folds to constants after unroll
    const short* W = Wset + m * 16384;

    // hoist A: 8 independent 16B loads (2 tiles x 4 k-slices)
    bf16x8 af[2][4];
#pragma unroll
    for (int t = 0; t < 2; ++t) {
      int row = row_base + t * 16 + r;
      int rowc = row < N ? row : N - 1;
      const short* Xr = X + (size_t)rowc * H + quad * 8;
#pragma unroll
      for (int kk = 0; kk < 4; ++kk) af[t][kk] = *(const bf16x8*)(Xr + kk * 32);
    }

#pragma unroll
    for (int kk = 0; kk < 4; ++kk) {
#pragma unroll
      for (int jt = 0; jt < 8; ++jt) {
        bf16x8 bf = *(const bf16x8*)(W + (((jt * 4 + kk) * 64 + lane) << 3));
        acc[0][jt] = __builtin_amdgcn_mfma_f32_16x16x32_bf16(af[0][kk], bf, acc[0][jt], 0, 0, 0);
        acc[1][jt] = __builtin_amdgcn_mfma_f32_16x16x32_bf16(af[1][kk], bf, acc[1][jt], 0, 0, 0);
      }
    }
  }

#pragma unroll
  for (int t = 0; t < 2; ++t) {
#pragma unroll
    for (int jt = 0; jt < 8; ++jt) {
      int ocol = jt * 16 + r;
      float b = bias[ocol];
#pragma unroll
      for (int g = 0; g < 4; ++g) {
        int orow = row_base + t * 16 + quad * 4 + g;
        if (orow < N) {
          float v = acc[t][jt][g] + b;
          if (relu) v = fmaxf(v, 0.f);
          if (out32) out32[(size_t)orow * H + ocol] = v;
          if (out16) out16[(size_t)orow * H + ocol] = f2bf(v);
        }
      }
    }
  }
}

extern "C" void kernel_launch(void* const* d_in, const int* in_sizes, int n_in,
                              void* d_out, int out_size, void* d_ws, size_t ws_size,
                              hipStream_t stream) {
  const float* emb_user = (const float*)d_in[0];
  const float* emb_post = (const float*)d_in[1];
  const float* W_l = (const float*)d_in[2];
  const float* b_l = (const float*)d_in[3];
  const float* W_r = (const float*)d_in[4];
  const int* ev_s = (const int*)d_in[5];
  const int* ev_d = (const int*)d_in[6];
  const int* el_s = (const int*)d_in[7];
  const int* el_d = (const int*)d_in[8];

  const int NU = in_sizes[0] / H;
  const int NP = in_sizes[1] / H;
  const int EV = in_sizes[5];
  const int EL = in_sizes[7];
  const int T = 2 * NP + 2 * NU;
  const size_t NUH = (size_t)NU * H, NPH = (size_t)NP * H;

  // workspace carve (256B-aligned bumps)
  char* p = (char*)d_ws;
  auto alloc = [&](size_t bytes) -> void* {
    void* q = (void*)p; p += (bytes + 255) & ~(size_t)255; return q;
  };
  int*   cnt   = (int*)alloc((size_t)T * 4);
  int*   cur   = (int*)alloc((size_t)T * 4);
  int*   off   = (int*)alloc((size_t)T * 4);
  int*   bsums = (int*)alloc(4 * 256 * 4);
  float* rcp   = (float*)alloc((size_t)T * 4);
  int*   sV_p  = (int*)alloc((size_t)EV * 4);
  int*   sV_u  = (int*)alloc((size_t)EV * 4);
  int*   sL_p  = (int*)alloc((size_t)EL * 4);
  int*   sL_u  = (int*)alloc((size_t)EL * 4);
  short* Wbf   = (short*)alloc((size_t)4 * 3 * 16384 * 2);
  float* bc    = (float*)alloc(4 * H * 4);
  short* xbf_u  = (short*)alloc(NUH * 2);
  short* xbf_p  = (short*)alloc(NPH * 2);
  short* xbf1_u = (short*)alloc(NUH * 2);
  short* xbf1_p = (short*)alloc(NPH * 2);
  short* mV     = (short*)alloc(NPH * 2);   // sized for posts, reused for users
  short* mL     = (short*)alloc(NPH * 2);

  float* out_u_final = (float*)d_out;
  float* out_p_final = (float*)d_out + NUH;

  // count-array index order: {V_p:0, L_p:NP, V_u:2NP, L_u:2NP+NU}
  const int oV_p = 0, oL_p = NP, oV_u = 2 * NP, oL_u = 2 * NP + NU;

  hipMemsetAsync(cnt, 0, (size_t)T * 4, stream);
  hipMemsetAsync(cur, 0, (size_t)T * 4, stream);
  count_edges<<<(EV + 255) / 256, 256, 0, stream>>>(ev_s, ev_d, EV, cnt + oV_u, cnt + oV_p);
  count_edges<<<(EL + 255) / 256, 256, 0, stream>>>(el_s, el_d, EL, cnt + oL_u, cnt + oL_p);
  rcp_from_cnt<<<(T + 255) / 256, 256, 0, stream>>>(cnt, rcp, T);

  int4 starts = { oV_p, oL_p, oV_u, oL_u };
  int4 lens   = { NP, NP, NU, NU };
  int maxb = ((NP > NU ? NP : NU) + 1023) / 1024;
  dim3 gscan(maxb, 4, 1);
  scan_k1<<<gscan, 256, 0, stream>>>(cnt, off, bsums, starts, lens);
  scan_k2<<<4, 256, 0, stream>>>(bsums, lens);
  scan_k3<<<gscan, 256, 0, stream>>>(off, bsums, starts, lens);

  fill_csr<<<(EV + 255) / 256, 256, 0, stream>>>(ev_s, ev_d, EV,
                                                 off + oV_p, cur + oV_p, sV_p,
                                                 off + oV_u, cur + oV_u, sV_u);
  fill_csr<<<(EL + 255) / 256, 256, 0, stream>>>(el_s, el_d, EL,
                                                 off + oL_p, cur + oL_p, sL_p,
                                                 off + oL_u, cur + oL_u, sL_u);

  cvt_bf16<<<((int)(NUH / 4) + 255) / 256, 256, 0, stream>>>(emb_user, xbf_u, (int)NUH);
  cvt_bf16<<<((int)(NPH / 4) + 255) / 256, 256, 0, stream>>>(emb_post, xbf_p, (int)NPH);
  prep_weights<<<(4 * 16384 + 255) / 256, 256, 0, stream>>>(W_l, b_l, W_r, Wbf, bc);

  for (int l = 0; l < 2; ++l) {
    const short* xu = l ? xbf1_u : xbf_u;
    const short* xp = l ? xbf1_p : xbf_p;
    const short* Wpost = Wbf + (size_t)(l * 2 + 0) * 3 * 16384;
    const short* Wuser = Wbf + (size_t)(l * 2 + 1) * 3 * 16384;
    const float* bpost = bc + (l * 2 + 0) * H;
    const float* buser = bc + (l * 2 + 1) * H;

    // posts: mean over incoming users (viewed, liked), then fused transform
    aggregate<<<(NP * 16 + 255) / 256, 256, 0, stream>>>(
        (const bf16x8*)xu, sV_p, off + oV_p, cnt + oV_p, rcp + oV_p,
        sL_p, off + oL_p, cnt + oL_p, rcp + oL_p,
        (bf16x8*)mV, (bf16x8*)mL, NP);
    fused_gemm<<<(NP + 127) / 128, 256, 0, stream>>>(
        mV, mL, xp, Wpost, bpost,
        l ? out_p_final : nullptr, l ? nullptr : xbf1_p, NP, l == 0);

    // users: mean over incoming posts (rev_viewed, rev_liked), then fused transform
    aggregate<<<(NU * 16 + 255) / 256, 256, 0, stream>>>(
        (const bf16x8*)xp, sV_u, off + oV_u, cnt + oV_u, rcp + oV_u,
        sL_u, off + oL_u, cnt + oL_u, rcp + oL_u,
        (bf16x8*)mV, (bf16x8*)mL, NU);
    fused_gemm<<<(NU + 127) / 128, 256, 0, stream>>>(
        mV, mL, xu, Wuser, buser,
        l ? out_u_final : nullptr, l ? nullptr : xbf1_u, NU, l == 0);
  }
}

// Round 2
// 738.378 us; speedup vs baseline: 1.3830x; 1.3830x over previous
//
#include <hip/hip_runtime.h>
#include <hip/hip_bf16.h>

#define H 128

using bf16x8  = __attribute__((ext_vector_type(8))) short;  // 8 bf16 = 4 VGPRs
using floatx4 = __attribute__((ext_vector_type(4))) float;

static __device__ __forceinline__ short f2bf(float f) {
  union { float f; unsigned u; } v; v.f = f;
  unsigned r = v.u + 0x7fffu + ((v.u >> 16) & 1u);  // RNE
  return (short)(r >> 16);
}
static __device__ __forceinline__ float bf2f(short s) {
  union { unsigned u; float f; } v; v.u = ((unsigned)(unsigned short)s) << 16;
  return v.f;
}

// ---- degree counts (int) ----
__global__ void count_edges(const int* __restrict__ src, const int* __restrict__ dst,
                            int E, int* __restrict__ cnt_s, int* __restrict__ cnt_d) {
  int e = blockIdx.x * blockDim.x + threadIdx.x;
  if (e >= E) return;
  atomicAdd(&cnt_s[src[e]], 1);
  atomicAdd(&cnt_d[dst[e]], 1);
}

__global__ void rcp_from_cnt(const int* __restrict__ cnt, float* __restrict__ r, int n) {
  int i = blockIdx.x * blockDim.x + threadIdx.x;
  if (i < n) r[i] = 1.0f / fmaxf((float)cnt[i], 1.0f);
}

// ---- 3-kernel exclusive scan over 4 contiguous count arrays ----
__global__ __launch_bounds__(256) void scan_k1(const int* __restrict__ cnt, int* __restrict__ off,
                                               int* __restrict__ bsums, int4 starts, int4 lens) {
  int a = blockIdx.y;
  int start = ((const int*)&starts)[a];
  int len   = ((const int*)&lens)[a];
  int chunk = blockIdx.x * 1024;
  if (chunk >= len) return;
  const int* in = cnt + start;
  int* out = off + start;
  int tid = threadIdx.x;
  int base = chunk + tid * 4;
  int v[4];
#pragma unroll
  for (int j = 0; j < 4; ++j) v[j] = (base + j < len) ? in[base + j] : 0;
  int s = v[0] + v[1] + v[2] + v[3];
  __shared__ int lds[256];
  lds[tid] = s; __syncthreads();
  for (int o = 1; o < 256; o <<= 1) {
    int t = (tid >= o) ? lds[tid - o] : 0;
    __syncthreads();
    lds[tid] += t;
    __syncthreads();
  }
  int run = lds[tid] - s;  // exclusive prefix of this thread's 4
#pragma unroll
  for (int j = 0; j < 4; ++j) { if (base + j < len) out[base + j] = run; run += v[j]; }
  if (tid == 255) bsums[a * 256 + blockIdx.x] = lds[255];
}

__global__ __launch_bounds__(256) void scan_k2(int* __restrict__ bsums, int4 lens) {
  int a = blockIdx.x;
  int len = ((const int*)&lens)[a];
  int nb = (len + 1023) >> 10;
  int tid = threadIdx.x;
  int s = (tid < nb) ? bsums[a * 256 + tid] : 0;  // guard: slots >= nb are poisoned
  __shared__ int lds[256];
  lds[tid] = s; __syncthreads();
  for (int o = 1; o < 256; o <<= 1) {
    int t = (tid >= o) ? lds[tid - o] : 0;
    __syncthreads();
    lds[tid] += t;
    __syncthreads();
  }
  bsums[a * 256 + tid] = lds[tid] - s;
}

__global__ __launch_bounds__(256) void scan_k3(int* __restrict__ off, const int* __restrict__ bsums,
                                               int4 starts, int4 lens) {
  int a = blockIdx.y;
  int start = ((const int*)&starts)[a];
  int len   = ((const int*)&lens)[a];
  int chunk = blockIdx.x * 1024;
  if (chunk >= len) return;
  int add = bsums[a * 256 + blockIdx.x];
  int* out = off + start;
  int base = chunk + threadIdx.x * 4;
#pragma unroll
  for (int j = 0; j < 4; ++j) if (base + j < len) out[base + j] += add;
}

// ---- CSR fill (both directions of one relation) ----
__global__ void fill_csr(const int* __restrict__ src, const int* __restrict__ dst, int E,
                         const int* __restrict__ off_d, int* __restrict__ cur_d, int* __restrict__ sort_d,
                         const int* __restrict__ off_s, int* __restrict__ cur_s, int* __restrict__ sort_s) {
  int e = blockIdx.x * blockDim.x + threadIdx.x;
  if (e >= E) return;
  int s = src[e], d = dst[e];
  sort_d[off_d[d] + atomicAdd(&cur_d[d], 1)] = s;  // neighbors of dst node (src ids)
  sort_s[off_s[s] + atomicAdd(&cur_s[s], 1)] = d;  // neighbors of src node (dst ids)
}

// ---- fp32 -> bf16 streaming convert ----
__global__ void cvt_bf16(const float* __restrict__ in, short* __restrict__ out, int n) {
  int idx = (blockIdx.x * blockDim.x + threadIdx.x) * 4;
  if (idx >= n) return;
  float4 v = *(const float4*)(in + idx);
  short4 o = { f2bf(v.x), f2bf(v.y), f2bf(v.z), f2bf(v.w) };
  *(short4*)(out + idx) = o;
}

// ---- weight prep: bf16 convert, combine Wr pair and bias pair per (layer,type).
// Weights written in MFMA B-fragment order:
//   fragment (jt,kk), lane l holds 8 bf16 of W[(jt*16 + (l&15))][kk*32 + (l>>4)*8 + j]
//   stored at ((jt*4+kk)*64 + l)*8 + j
// fused_gemm2 stages this linearly into LDS (layout already fragment-ordered).
static __device__ __forceinline__ int wswz(int e) {
  int n = e >> 7, k = e & 127;          // W row-major [n][k]
  int jt = n >> 4, r = n & 15;
  int kk = k >> 5, q = (k >> 3) & 3, j = k & 7;
  return (((jt * 4 + kk) * 64 + q * 16 + r) << 3) + j;
}
__global__ void prep_weights(const float* __restrict__ W_l, const float* __restrict__ b_l,
                             const float* __restrict__ W_r,
                             short* __restrict__ Wbf, float* __restrict__ bc) {
  int i = blockIdx.x * blockDim.x + threadIdx.x;
  if (i >= 4 * 16384) return;
  int s = i >> 14, e = i & 16383;
  int l = s >> 1, t = s & 1;
  int rA = t ? 1 : 0, rB = t ? 3 : 2;
  const float* WA = W_l + ((size_t)(l * 4 + rA) << 14);
  const float* WB = W_l + ((size_t)(l * 4 + rB) << 14);
  const float* RA = W_r + ((size_t)(l * 4 + rA) << 14);
  const float* RB = W_r + ((size_t)(l * 4 + rB) << 14);
  short* o = Wbf + (size_t)s * 3 * 16384;
  int d = wswz(e);
  o[d]             = f2bf(WA[e]);
  o[16384 + d]     = f2bf(WB[e]);
  o[2 * 16384 + d] = f2bf(RA[e] + RB[e]);
  if (e < H) bc[s * H + e] = b_l[(l * 4 + rA) * H + e] + b_l[(l * 4 + rB) * H + e];
}

// ---- fused segment-mean for BOTH parts (posts + users) in one launch.
// 16 lanes per node, bf16x8 per lane, fp32 accum. Edge loop unrolled x4 so
// 4 independent 16B gathers are in flight (was 1 -> serial L3 latency).
__global__ __launch_bounds__(256) void aggregate2(
    const bf16x8* __restrict__ xA,
    const int* __restrict__ sVA, const int* __restrict__ oVA, const int* __restrict__ cVA, const float* __restrict__ rVA,
    const int* __restrict__ sLA, const int* __restrict__ oLA, const int* __restrict__ cLA, const float* __restrict__ rLA,
    bf16x8* __restrict__ mVA, bf16x8* __restrict__ mLA, int NA, int nbA,
    const bf16x8* __restrict__ xB,
    const int* __restrict__ sVB, const int* __restrict__ oVB, const int* __restrict__ cVB, const float* __restrict__ rVB,
    const int* __restrict__ sLB, const int* __restrict__ oLB, const int* __restrict__ cLB, const float* __restrict__ rLB,
    bf16x8* __restrict__ mVB, bf16x8* __restrict__ mLB, int NB) {
  int b = blockIdx.x;
  const bf16x8* x; const int *sV, *oV, *cV, *sL, *oL, *cL;
  const float *rV, *rL; bf16x8 *mV, *mL; int N, t0;
  if (b < nbA) {
    x = xA; sV = sVA; oV = oVA; cV = cVA; rV = rVA; sL = sLA; oL = oLA; cL = cLA; rL = rLA;
    mV = mVA; mL = mLA; N = NA; t0 = b * 256;
  } else {
    x = xB; sV = sVB; oV = oVB; cV = cVB; rV = rVB; sL = sLB; oL = oLB; cL = cLB; rL = rLB;
    mV = mVB; mL = mLB; N = NB; t0 = (b - nbA) * 256;
  }
  int t = t0 + threadIdx.x;
  int node = t >> 4, c = t & 15;
  if (node >= N) return;

  float acc[8];
  {
    int o = oV[node], e = o + cV[node];
#pragma unroll
    for (int j = 0; j < 8; ++j) acc[j] = 0.f;
    int i = o;
    for (; i + 4 <= e; i += 4) {
      int s0 = sV[i], s1 = sV[i + 1], s2 = sV[i + 2], s3 = sV[i + 3];
      bf16x8 v0 = x[(size_t)s0 * 16 + c];
      bf16x8 v1 = x[(size_t)s1 * 16 + c];
      bf16x8 v2 = x[(size_t)s2 * 16 + c];
      bf16x8 v3 = x[(size_t)s3 * 16 + c];
#pragma unroll
      for (int j = 0; j < 8; ++j) acc[j] += bf2f(v0[j]);
#pragma unroll
      for (int j = 0; j < 8; ++j) acc[j] += bf2f(v1[j]);
#pragma unroll
      for (int j = 0; j < 8; ++j) acc[j] += bf2f(v2[j]);
#pragma unroll
      for (int j = 0; j < 8; ++j) acc[j] += bf2f(v3[j]);
    }
    for (; i < e; ++i) {
      bf16x8 v = x[(size_t)sV[i] * 16 + c];
#pragma unroll
      for (int j = 0; j < 8; ++j) acc[j] += bf2f(v[j]);
    }
    float r = rV[node];
    bf16x8 w;
#pragma unroll
    for (int j = 0; j < 8; ++j) w[j] = f2bf(acc[j] * r);
    mV[(size_t)node * 16 + c] = w;
  }
  {
    int o = oL[node], e = o + cL[node];
#pragma unroll
    for (int j = 0; j < 8; ++j) acc[j] = 0.f;
    int i = o;
    for (; i + 4 <= e; i += 4) {
      int s0 = sL[i], s1 = sL[i + 1], s2 = sL[i + 2], s3 = sL[i + 3];
      bf16x8 v0 = x[(size_t)s0 * 16 + c];
      bf16x8 v1 = x[(size_t)s1 * 16 + c];
      bf16x8 v2 = x[(size_t)s2 * 16 + c];
      bf16x8 v3 = x[(size_t)s3 * 16 + c];
#pragma unroll
      for (int j = 0; j < 8; ++j) acc[j] += bf2f(v0[j]);
#pragma unroll
      for (int j = 0; j < 8; ++j) acc[j] += bf2f(v1[j]);
#pragma unroll
      for (int j = 0; j < 8; ++j) acc[j] += bf2f(v2[j]);
#pragma unroll
      for (int j = 0; j < 8; ++j) acc[j] += bf2f(v3[j]);
    }
    for (; i < e; ++i) {
      bf16x8 v = x[(size_t)sL[i] * 16 + c];
#pragma unroll
      for (int j = 0; j < 8; ++j) acc[j] += bf2f(v[j]);
    }
    float r = rL[node];
    bf16x8 w;
#pragma unroll
    for (int j = 0; j < 8; ++j) w[j] = f2bf(acc[j] * r);
    mL[(size_t)node * 16 + c] = w;
  }
}

// ---- fused SAGE transform v3: out = mV@WA.T + mL@WB.T + x@WRc.T + b [, ReLU]
// Both parts (posts+users) in ONE launch: 256 blocks x 512 threads, 96KB dynamic
// LDS. All 3 weight matrices staged ONCE per block (fragment-order, linear copy),
// exactly one __syncthreads, then 8 waves free-run over 32-row groups with a
// 3-deep rotating A-fragment pipeline (issue batch n+2 while MFMA-ing batch n).
// A frag: A[m=lane&15][k=quad*8+j]; B frag: B[k][n=lane&15]=W[n][k];
// C/D: col=lane&15, row=quad*4+reg.
__global__ __launch_bounds__(512, 2) void fused_gemm2(
    const short* __restrict__ mVA, const short* __restrict__ mLA, const short* __restrict__ xbA,
    const short* __restrict__ WA, const float* __restrict__ biasA,
    float* __restrict__ o32A, short* __restrict__ o16A, int NA, int nbA,
    const short* __restrict__ mVB, const short* __restrict__ mLB, const short* __restrict__ xbB,
    const short* __restrict__ WB, const float* __restrict__ biasB,
    float* __restrict__ o32B, short* __restrict__ o16B, int NB, int relu) {
  extern __shared__ short Wlds[];  // 3 * 16384 shorts = 96 KB
  int b = blockIdx.x;
  const short *mV, *mL, *xb, *W; const float* bias;
  float* out32; short* out16; int N, nbPart, bLoc;
  if (b < nbA) {
    mV = mVA; mL = mLA; xb = xbA; W = WA; bias = biasA;
    out32 = o32A; out16 = o16A; N = NA; nbPart = nbA; bLoc = b;
  } else {
    mV = mVB; mL = mLB; xb = xbB; W = WB; bias = biasB;
    out32 = o32B; out16 = o16B; N = NB; nbPart = 256 - nbA; bLoc = b - nbA;
  }

  int tid = threadIdx.x;
  // stage all 3 matrices (6144 x 16B chunks), coalesced linear copy
#pragma unroll
  for (int it = 0; it < 12; ++it) {
    int c = it * 512 + tid;
    *(bf16x8*)(Wlds + (size_t)c * 8) = *(const bf16x8*)(W + (size_t)c * 8);
  }
  __syncthreads();  // the ONLY barrier

  int wave = tid >> 6, lane = tid & 63;
  int r = lane & 15, quad = lane >> 4;

  // preload bias for this lane's 8 output columns
  float bias_r[8];
#pragma unroll
  for (int jt = 0; jt < 8; ++jt) bias_r[jt] = bias[jt * 16 + r];

  // rowgroup (32 rows) assignment: stride-interleaved across all waves of part
  int nrgTot = (N + 31) >> 5;
  int wStride = nbPart * 8;
  int wBase = bLoc * 8 + wave;
  int nrgW = (wBase < nrgTot) ? (nrgTot - wBase + wStride - 1) / wStride : 0;

  floatx4 acc[2][8];
#pragma unroll
  for (int t = 0; t < 2; ++t)
#pragma unroll
    for (int j = 0; j < 8; ++j) acc[t][j] = floatx4{0.f, 0.f, 0.f, 0.f};

  auto issueA = [&](int j, int m, bf16x8 (&buf)[2][4]) {
    if (j >= nrgW) return;  // wave-uniform
    int rg = wBase + j * wStride;
    int rowb = rg << 5;
    const short* X = (m == 0) ? mV : (m == 1) ? mL : xb;
#pragma unroll
    for (int t = 0; t < 2; ++t) {
      int row = rowb + t * 16 + r;
      row = row < N ? row : N - 1;
      const short* Xr = X + (size_t)row * H + quad * 8;
#pragma unroll
      for (int kk = 0; kk < 4; ++kk) buf[t][kk] = *(const bf16x8*)(Xr + kk * 32);
    }
  };

  auto computeB = [&](int m, bf16x8 (&buf)[2][4]) {
    const short* Wm = Wlds + m * 16384;
#pragma unroll
    for (int kk = 0; kk < 4; ++kk) {
#pragma unroll
      for (int jt = 0; jt < 8; ++jt) {
        bf16x8 bfR = *(const bf16x8*)(Wm + (size_t)((jt * 4 + kk) * 64 + lane) * 8);
        acc[0][jt] = __builtin_amdgcn_mfma_f32_16x16x32_bf16(buf[0][kk], bfR, acc[0][jt], 0, 0, 0);
        acc[1][jt] = __builtin_amdgcn_mfma_f32_16x16x32_bf16(buf[1][kk], bfR, acc[1][jt], 0, 0, 0);
      }
    }
  };

  auto epi = [&](int j) {
    int rowb = (wBase + j * wStride) << 5;
#pragma unroll
    for (int t = 0; t < 2; ++t) {
#pragma unroll
      for (int jt = 0; jt < 8; ++jt) {
        int ocol = jt * 16 + r;
        float bv = bias_r[jt];
#pragma unroll
        for (int g = 0; g < 4; ++g) {
          int orow = rowb + t * 16 + quad * 4 + g;
          if (orow < N) {
            float v = acc[t][jt][g] + bv;
            if (relu) v = fmaxf(v, 0.f);
            if (out32) out32[(size_t)orow * H + ocol] = v;
            else       out16[(size_t)orow * H + ocol] = f2bf(v);
          }
        }
        acc[t][jt] = floatx4{0.f, 0.f, 0.f, 0.f};
      }
    }
  };

  bf16x8 A0[2][4], A1[2][4], A2[2][4];
  issueA(0, 0, A0);
  issueA(0, 1, A1);
  for (int j = 0; j < nrgW; ++j) {
    issueA(j, 2, A2);
    computeB(0, A0);
    issueA(j + 1, 0, A0);
    computeB(1, A1);
    issueA(j + 1, 1, A1);
    computeB(2, A2);
    epi(j);
  }
}

extern "C" void kernel_launch(void* const* d_in, const int* in_sizes, int n_in,
                              void* d_out, int out_size, void* d_ws, size_t ws_size,
                              hipStream_t stream) {
  const float* emb_user = (const float*)d_in[0];
  const float* emb_post = (const float*)d_in[1];
  const float* W_l = (const float*)d_in[2];
  const float* b_l = (const float*)d_in[3];
  const float* W_r = (const float*)d_in[4];
  const int* ev_s = (const int*)d_in[5];
  const int* ev_d = (const int*)d_in[6];
  const int* el_s = (const int*)d_in[7];
  const int* el_d = (const int*)d_in[8];

  const int NU = in_sizes[0] / H;
  const int NP = in_sizes[1] / H;
  const int EV = in_sizes[5];
  const int EL = in_sizes[7];
  const int T = 2 * NP + 2 * NU;
  const size_t NUH = (size_t)NU * H, NPH = (size_t)NP * H;

  // workspace carve (256B-aligned bumps)
  char* p = (char*)d_ws;
  auto alloc = [&](size_t bytes) -> void* {
    void* q = (void*)p; p += (bytes + 255) & ~(size_t)255; return q;
  };
  int*   cnt   = (int*)alloc((size_t)T * 4);
  int*   cur   = (int*)alloc((size_t)T * 4);
  int*   off   = (int*)alloc((size_t)T * 4);
  int*   bsums = (int*)alloc(4 * 256 * 4);
  float* rcp   = (float*)alloc((size_t)T * 4);
  int*   sV_p  = (int*)alloc((size_t)EV * 4);
  int*   sV_u  = (int*)alloc((size_t)EV * 4);
  int*   sL_p  = (int*)alloc((size_t)EL * 4);
  int*   sL_u  = (int*)alloc((size_t)EL * 4);
  short* Wbf   = (short*)alloc((size_t)4 * 3 * 16384 * 2);
  float* bc    = (float*)alloc(4 * H * 4);
  short* xbf_u  = (short*)alloc(NUH * 2);
  short* xbf_p  = (short*)alloc(NPH * 2);
  short* xbf1_u = (short*)alloc(NUH * 2);
  short* xbf1_p = (short*)alloc(NPH * 2);
  short* mVp    = (short*)alloc(NPH * 2);
  short* mLp    = (short*)alloc(NPH * 2);
  short* mVu    = (short*)alloc(NUH * 2);
  short* mLu    = (short*)alloc(NUH * 2);

  float* out_u_final = (float*)d_out;
  float* out_p_final = (float*)d_out + NUH;

  // count-array index order: {V_p:0, L_p:NP, V_u:2NP, L_u:2NP+NU}
  const int oV_p = 0, oL_p = NP, oV_u = 2 * NP, oL_u = 2 * NP + NU;

  hipMemsetAsync(cnt, 0, (size_t)T * 4, stream);
  hipMemsetAsync(cur, 0, (size_t)T * 4, stream);
  count_edges<<<(EV + 255) / 256, 256, 0, stream>>>(ev_s, ev_d, EV, cnt + oV_u, cnt + oV_p);
  count_edges<<<(EL + 255) / 256, 256, 0, stream>>>(el_s, el_d, EL, cnt + oL_u, cnt + oL_p);
  rcp_from_cnt<<<(T + 255) / 256, 256, 0, stream>>>(cnt, rcp, T);

  int4 starts = { oV_p, oL_p, oV_u, oL_u };
  int4 lens   = { NP, NP, NU, NU };
  int maxb = ((NP > NU ? NP : NU) + 1023) / 1024;
  dim3 gscan(maxb, 4, 1);
  scan_k1<<<gscan, 256, 0, stream>>>(cnt, off, bsums, starts, lens);
  scan_k2<<<4, 256, 0, stream>>>(bsums, lens);
  scan_k3<<<gscan, 256, 0, stream>>>(off, bsums, starts, lens);

  fill_csr<<<(EV + 255) / 256, 256, 0, stream>>>(ev_s, ev_d, EV,
                                                 off + oV_p, cur + oV_p, sV_p,
                                                 off + oV_u, cur + oV_u, sV_u);
  fill_csr<<<(EL + 255) / 256, 256, 0, stream>>>(el_s, el_d, EL,
                                                 off + oL_p, cur + oL_p, sL_p,
                                                 off + oL_u, cur + oL_u, sL_u);

  cvt_bf16<<<((int)(NUH / 4) + 255) / 256, 256, 0, stream>>>(emb_user, xbf_u, (int)NUH);
  cvt_bf16<<<((int)(NPH / 4) + 255) / 256, 256, 0, stream>>>(emb_post, xbf_p, (int)NPH);
  prep_weights<<<(4 * 16384 + 255) / 256, 256, 0, stream>>>(W_l, b_l, W_r, Wbf, bc);

  // allow 96KB dynamic LDS for the fused GEMM
  hipFuncSetAttribute((const void*)fused_gemm2, hipFuncAttributeMaxDynamicSharedMemorySize,
                      3 * 16384 * 2);

  // gemm block split: proportional to row counts, 256 blocks total (1/CU)
  int nbP = (int)((256LL * NP) / ((long long)NP + NU));
  if (nbP < 1) nbP = 1;
  if (nbP > 255) nbP = 255;

  // aggregate grid split
  int nbAggP = (NP + 15) / 16;
  int nbAggU = (NU + 15) / 16;

  for (int l = 0; l < 2; ++l) {
    const short* xu = l ? xbf1_u : xbf_u;
    const short* xp = l ? xbf1_p : xbf_p;
    const short* Wpost = Wbf + (size_t)(l * 2 + 0) * 3 * 16384;
    const short* Wuser = Wbf + (size_t)(l * 2 + 1) * 3 * 16384;
    const float* bpost = bc + (l * 2 + 0) * H;
    const float* buser = bc + (l * 2 + 1) * H;

    // both aggregations (posts from users, users from posts) in one launch
    aggregate2<<<nbAggP + nbAggU, 256, 0, stream>>>(
        (const bf16x8*)xu,
        sV_p, off + oV_p, cnt + oV_p, rcp + oV_p,
        sL_p, off + oL_p, cnt + oL_p, rcp + oL_p,
        (bf16x8*)mVp, (bf16x8*)mLp, NP, nbAggP,
        (const bf16x8*)xp,
        sV_u, off + oV_u, cnt + oV_u, rcp + oV_u,
        sL_u, off + oL_u, cnt + oL_u, rcp + oL_u,
        (bf16x8*)mVu, (bf16x8*)mLu, NU);

    // both transforms in one launch
    fused_gemm2<<<256, 512, 3 * 16384 * 2, stream>>>(
        mVp, mLp, xp, Wpost, bpost,
        l ? out_p_final : nullptr, l ? nullptr : xbf1_p, NP, nbP,
        mVu, mLu, xu, Wuser, buser,
        l ? out_u_final : nullptr, l ? nullptr : xbf1_u, NU, l == 0);
  }
}